// Round 3
// baseline (564.471 us; speedup 1.0000x reference)
//
#include <hip/hip_runtime.h>
#include <hip/hip_fp16.h>
#include <math.h>
#include <float.h>

// ---------------------------------------------------------------------------
// S_E epidemic step:
//   E' = relu(E-1); sus = (E==inf)*susceptiveness; infv = (E<=1)*infectiveness
//   acc[src] += log(1 - sus[src]*infv[dst])   over 32M edges (scatter-atomic)
//   out = (rand < 1-exp(acc)) ? incubation : E'
//
// R8: R6/R7 edge kernel was latency-serialization-bound (HBM 21%, VALU 7%):
// the per-edge chain {stream load -> LDS bit -> sus gather -> infv gather ->
// atomic} serialized, and R7's in-loop masking was defeated by codegen
// (VGPR 64, occupancy 33%). R8 splits structurally:
//   E1 edge_filter: stream + LDS infective-bitmask test + compact surviving
//      (s,d) pairs (~30% = 9.6M x 8B) via wave scan + per-block atomic
//      reservation. Pure streaming, no gathers -> BW-bound.
//   E2 edge_process: dense survivors, no LDS -> full occupancy; every lane
//      does a useful sus gather, masked infv gather, conditional atomic.
// Overflow-safe: survivors past capacity processed inline in E1.
// Accumulation in log2 domain; final applies exp2f. acc lives in d_out.
// Epilogue scrubs non-finite bits.
// ---------------------------------------------------------------------------

typedef int v4i __attribute__((ext_vector_type(4)));

#define MAX_BIT_WORDS 32768   // u32 words -> 128 KiB LDS, supports n <= 1,048,576

__global__ void prep_full(const float* __restrict__ E,
                          const float* __restrict__ susc,
                          const float* __restrict__ infc,
                          __half* __restrict__ sus,
                          __half* __restrict__ infv,
                          unsigned long long* __restrict__ gbits, // may be null
                          unsigned int* __restrict__ gctr,        // may be null
                          float* __restrict__ acc,
                          int n) {
    int i = blockIdx.x * blockDim.x + threadIdx.x;
    float e = (i < n) ? E[i] : 2.0f;             // default: neither mask
    bool infective = (i < n) && (e <= 1.0f);
    unsigned long long m = __ballot(infective);  // wave64 ballot, all lanes
    if (i < n) {
        sus[i]  = __float2half(isinf(e) ? susc[i] : 0.0f);    // susceptible: E == inf
        infv[i] = __float2half(infective ? infc[i] : 0.0f);   // infective: E <= 1
        acc[i]  = 0.0f;
    }
    if (gbits && (threadIdx.x & 63) == 0 && i < n) {
        gbits[i >> 6] = m;                        // u32 word i>>5, bit i&31
    }
    if (gctr && blockIdx.x == 0 && threadIdx.x == 0) *gctr = 0;
}

__global__ void prep_acc_only(float* __restrict__ acc, int n) {
    int i = blockIdx.x * blockDim.x + threadIdx.x;
    if (i < n) acc[i] = 0.0f;
}

// ---------------------------------------------------------------------------
// R8 E1: stream edges, LDS bitmask filter, compact survivors to pairs[].
// ---------------------------------------------------------------------------
__global__ __launch_bounds__(1024, 4) void edge_filter(
        const int* __restrict__ src,
        const int* __restrict__ dst,
        const unsigned int* __restrict__ gbits,
        const unsigned short* __restrict__ susu,
        const unsigned short* __restrict__ infvu,
        float* __restrict__ acc,
        unsigned long long* __restrict__ pairs,
        unsigned int* __restrict__ gctr,
        unsigned int capacity,
        int n_edges, int nwords) {
    __shared__ unsigned int bits[MAX_BIT_WORDS];
    __shared__ unsigned int wave_cnt[16];
    __shared__ unsigned int wave_base[16];
    for (int w = threadIdx.x; w < nwords; w += 1024)
        bits[w] = gbits[w];
    __syncthreads();

    const int lane = threadIdx.x & 63;
    const int wid  = threadIdx.x >> 6;

    long long nchunk = (long long)n_edges >> 3;        // 8 edges/chunk
    long long stride = (long long)gridDim.x * blockDim.x;

    for (long long cb = (long long)blockIdx.x * blockDim.x; cb < nchunk; cb += stride) {
        long long c = cb + threadIdx.x;                // block-uniform loop, per-thread chunk
        bool active = c < nchunk;

        int ss[8], dd[8];
        unsigned pm = 0;
        if (active) {
            v4i s0 = __builtin_nontemporal_load((const v4i*)src + 2 * c);
            v4i s1 = __builtin_nontemporal_load((const v4i*)src + 2 * c + 1);
            v4i d0 = __builtin_nontemporal_load((const v4i*)dst + 2 * c);
            v4i d1 = __builtin_nontemporal_load((const v4i*)dst + 2 * c + 1);
            ss[0]=s0.x; ss[1]=s0.y; ss[2]=s0.z; ss[3]=s0.w;
            ss[4]=s1.x; ss[5]=s1.y; ss[6]=s1.z; ss[7]=s1.w;
            dd[0]=d0.x; dd[1]=d0.y; dd[2]=d0.z; dd[3]=d0.w;
            dd[4]=d1.x; dd[5]=d1.y; dd[6]=d1.z; dd[7]=d1.w;
#pragma unroll
            for (int k = 0; k < 8; ++k)
                pm |= ((bits[dd[k] >> 5] >> (dd[k] & 31)) & 1u) << k;
        }
        int cnt = __popc(pm);

        // wave64 inclusive scan of cnt
        int scan = cnt;
#pragma unroll
        for (int off = 1; off < 64; off <<= 1) {
            int v = __shfl_up(scan, off, 64);
            if (lane >= off) scan += v;
        }
        if (lane == 63) wave_cnt[wid] = (unsigned)scan;  // wave total
        __syncthreads();
        if (threadIdx.x == 0) {
            unsigned run = 0;
#pragma unroll
            for (int w = 0; w < 16; ++w) { unsigned t = wave_cnt[w]; wave_cnt[w] = run; run += t; }
            unsigned base = run ? atomicAdd(gctr, run) : 0u;
#pragma unroll
            for (int w = 0; w < 16; ++w) wave_base[w] = base + wave_cnt[w];
        }
        __syncthreads();

        unsigned mybase = wave_base[wid] + (unsigned)(scan - cnt);
#pragma unroll
        for (int k = 0; k < 8; ++k) {
            if (pm & (1u << k)) {
                unsigned pos = mybase + (unsigned)__popc(pm & ((1u << k) - 1));
                if (pos < capacity) {
                    pairs[pos] = ((unsigned long long)(unsigned)dd[k] << 32)
                               | (unsigned long long)(unsigned)ss[k];
                } else {
                    // statistical-overflow safety net: process inline
                    unsigned short svu = susu[ss[k]];
                    if (svu) {
                        float sv = __half2float(__ushort_as_half(svu));
                        float iv = __half2float(__ushort_as_half(infvu[dd[k]]));
                        float p = sv * iv;
                        if (p != 0.0f) atomicAdd(&acc[ss[k]], __log2f(1.0f - p));
                    }
                }
            }
        }
    }

    // tail (n_edges % 8): inline, block 0
    long long tb = nchunk << 3;
    int tail = (int)(n_edges - tb);
    if (blockIdx.x == 0 && (int)threadIdx.x < tail) {
        long long e = tb + threadIdx.x;
        int d = dst[e];
        if ((bits[d >> 5] >> (d & 31)) & 1u) {
            int s = src[e];
            unsigned short svu = susu[s];
            if (svu) {
                float sv = __half2float(__ushort_as_half(svu));
                float iv = __half2float(__ushort_as_half(infvu[d]));
                float p = sv * iv;
                if (p != 0.0f) atomicAdd(&acc[s], __log2f(1.0f - p));
            }
        }
    }
}

// ---------------------------------------------------------------------------
// R8 E2: dense survivor processing. No LDS -> full occupancy, max TLP.
// ---------------------------------------------------------------------------
__global__ __launch_bounds__(256) void edge_process(
        const unsigned long long* __restrict__ pairs,
        const unsigned int* __restrict__ gctr,
        const unsigned short* __restrict__ susu,
        const unsigned short* __restrict__ infvu,
        float* __restrict__ acc,
        unsigned int capacity) {
    unsigned int m = *gctr;
    if (m > capacity) m = capacity;
    long long stride4 = (long long)gridDim.x * blockDim.x * 4;
    for (long long b = ((long long)blockIdx.x * blockDim.x + threadIdx.x) * 4;
         b < (long long)m; b += stride4) {
        unsigned long long p0, p1, p2, p3;
        bool w1, w2, w3;
        if (b + 3 < (long long)m) {
            const v4i* vp = (const v4i*)(pairs + b);   // 32B-aligned (b%4==0)
            v4i q0 = vp[0], q1 = vp[1];
            p0 = ((unsigned long long)(unsigned)q0.y << 32) | (unsigned)q0.x;
            p1 = ((unsigned long long)(unsigned)q0.w << 32) | (unsigned)q0.z;
            p2 = ((unsigned long long)(unsigned)q1.y << 32) | (unsigned)q1.x;
            p3 = ((unsigned long long)(unsigned)q1.w << 32) | (unsigned)q1.z;
            w1 = w2 = w3 = true;
        } else {
            w1 = b + 1 < (long long)m;
            w2 = b + 2 < (long long)m;
            w3 = b + 3 < (long long)m;
            p0 = pairs[b];
            p1 = w1 ? pairs[b + 1] : 0ull;
            p2 = w2 ? pairs[b + 2] : 0ull;
            p3 = w3 ? pairs[b + 3] : 0ull;
        }
        int s0 = (int)(p0 & 0xffffffffu), d0 = (int)(p0 >> 32);
        int s1 = (int)(p1 & 0xffffffffu), d1 = (int)(p1 >> 32);
        int s2 = (int)(p2 & 0xffffffffu), d2 = (int)(p2 >> 32);
        int s3 = (int)(p3 & 0xffffffffu), d3 = (int)(p3 >> 32);

        // phase: 4 parallel sus gathers (all indices valid)
        unsigned short a0 = susu[s0];
        unsigned short a1 = susu[s1];
        unsigned short a2 = susu[s2];
        unsigned short a3 = susu[s3];
        if (!w1) a1 = 0;
        if (!w2) a2 = 0;
        if (!w3) a3 = 0;

        // phase: 4 masked infv gathers (~50% useful; rest hit line 0)
        unsigned short i0 = infvu[a0 ? d0 : 0];
        unsigned short i1 = infvu[a1 ? d1 : 0];
        unsigned short i2 = infvu[a2 ? d2 : 0];
        unsigned short i3 = infvu[a3 ? d3 : 0];

        float pr0 = __half2float(__ushort_as_half(a0)) * __half2float(__ushort_as_half(i0));
        float pr1 = __half2float(__ushort_as_half(a1)) * __half2float(__ushort_as_half(i1));
        float pr2 = __half2float(__ushort_as_half(a2)) * __half2float(__ushort_as_half(i2));
        float pr3 = __half2float(__ushort_as_half(a3)) * __half2float(__ushort_as_half(i3));
        if (pr0 != 0.0f) atomicAdd(&acc[s0], __log2f(1.0f - pr0));
        if (pr1 != 0.0f) atomicAdd(&acc[s1], __log2f(1.0f - pr1));
        if (pr2 != 0.0f) atomicAdd(&acc[s2], __log2f(1.0f - pr2));
        if (pr3 != 0.0f) atomicAdd(&acc[s3], __log2f(1.0f - pr3));
    }
}

// ---------------------------------------------------------------------------
// Fallback (proven R6 path): LDS bitmask, divergent 8-edge loop. 262 us.
// ---------------------------------------------------------------------------
__global__ __launch_bounds__(1024, 4) void edge_lds(
        const int* __restrict__ src,
        const int* __restrict__ dst,
        const __half* __restrict__ sus,
        const __half* __restrict__ infv,
        const unsigned int* __restrict__ gbits,
        float* __restrict__ acc,
        int n_edges, int nwords) {
    __shared__ unsigned int bits[MAX_BIT_WORDS];
    for (int w = threadIdx.x; w < nwords; w += 1024)
        bits[w] = gbits[w];
    __syncthreads();

    const unsigned short* susu  = (const unsigned short*)sus;
    const unsigned short* infvu = (const unsigned short*)infv;

    long long nchunk = (long long)n_edges >> 3;
    long long stride = (long long)gridDim.x * blockDim.x;
    for (long long c = (long long)blockIdx.x * blockDim.x + threadIdx.x;
         c < nchunk; c += stride) {
        v4i s0 = __builtin_nontemporal_load((const v4i*)src + 2 * c);
        v4i s1 = __builtin_nontemporal_load((const v4i*)src + 2 * c + 1);
        v4i d0 = __builtin_nontemporal_load((const v4i*)dst + 2 * c);
        v4i d1 = __builtin_nontemporal_load((const v4i*)dst + 2 * c + 1);
        int ss[8] = {s0.x, s0.y, s0.z, s0.w, s1.x, s1.y, s1.z, s1.w};
        int dd[8] = {d0.x, d0.y, d0.z, d0.w, d1.x, d1.y, d1.z, d1.w};
#pragma unroll
        for (int k = 0; k < 8; ++k) {
            int d = dd[k];
            if ((bits[d >> 5] >> (d & 31)) & 1u) {
                int s = ss[k];
                unsigned short svu = susu[s];
                if (svu) {
                    float sv = __half2float(__ushort_as_half(svu));
                    float iv = __half2float(__ushort_as_half(infvu[d]));
                    float p = sv * iv;
                    if (p != 0.0f)
                        atomicAdd(&acc[s], __log2f(1.0f - p));
                }
            }
        }
    }

    long long tb = nchunk << 3;
    int tail = (int)(n_edges - tb);
    if (blockIdx.x == 0 && (int)threadIdx.x < tail) {
        long long e = tb + threadIdx.x;
        int d = dst[e];
        if ((bits[d >> 5] >> (d & 31)) & 1u) {
            int s = src[e];
            unsigned short svu = susu[s];
            if (svu) {
                float sv = __half2float(__ushort_as_half(svu));
                float iv = __half2float(__ushort_as_half(infvu[d]));
                float p = sv * iv;
                if (p != 0.0f)
                    atomicAdd(&acc[s], __log2f(1.0f - p));
            }
        }
    }
}

// ---------------------------------------------------------------------------
// Fallback A (n too big for LDS bitmask): R5 structure, log2 domain.
// ---------------------------------------------------------------------------
__global__ void edge_fast(const int* __restrict__ src,
                          const int* __restrict__ dst,
                          const __half* __restrict__ sus,
                          const __half* __restrict__ infv,
                          float* __restrict__ acc,
                          int n_edges) {
    int t = blockIdx.x * blockDim.x + threadIdx.x;
    long long base = (long long)t * 4;
    if (base + 3 < n_edges) {
        v4i s4 = __builtin_nontemporal_load((const v4i*)src + t);
        v4i d4 = __builtin_nontemporal_load((const v4i*)dst + t);
        int ss[4] = {s4.x, s4.y, s4.z, s4.w};
        int dd[4] = {d4.x, d4.y, d4.z, d4.w};
#pragma unroll
        for (int k = 0; k < 4; ++k) {
            float sv = __half2float(sus[ss[k]]);
            if (sv != 0.0f) {
                float iv = __half2float(infv[dd[k]]);
                if (iv != 0.0f) {
                    atomicAdd(&acc[ss[k]], __log2f(1.0f - sv * iv));
                }
            }
        }
    } else if (base < n_edges) {
        for (long long e = base; e < n_edges; ++e) {
            int s = src[e];
            float sv = __half2float(sus[s]);
            if (sv != 0.0f) {
                float iv = __half2float(infv[dst[e]]);
                if (iv != 0.0f) atomicAdd(&acc[s], __log2f(1.0f - sv * iv));
            }
        }
    }
}

// ---------------------------------------------------------------------------
// Fallback B (ws too small): recompute masks inline per edge, log2 domain.
// ---------------------------------------------------------------------------
__global__ void edge_inline(const int* __restrict__ src,
                            const int* __restrict__ dst,
                            const float* __restrict__ E,
                            const float* __restrict__ susc,
                            const float* __restrict__ infc,
                            float* __restrict__ acc,
                            int n_edges) {
    long long e = (long long)blockIdx.x * blockDim.x + threadIdx.x;
    if (e < n_edges) {
        int s = src[e];
        if (isinf(E[s])) {
            int d = dst[e];
            if (E[d] <= 1.0f) {
                atomicAdd(&acc[s], __log2f(1.0f - susc[s] * infc[d]));
            }
        }
    }
}

__global__ void final_kernel(const float* __restrict__ E,
                             const float* __restrict__ rnd,
                             const float* __restrict__ incub,
                             float* __restrict__ out,  // also holds acc (log2 domain)
                             int n) {
    int i = blockIdx.x * blockDim.x + threadIdx.x;
    if (i < n) {
        float a = out[i];                           // acc (in-place), sum of log2 terms
        float e_new = fmaxf(E[i] - 1.0f, 0.0f);     // relu(E-1)
        float p = 1.0f - exp2f(a);
        float r = (rnd[i] < p) ? incub[i] : e_new;
        // scrub non-finite (inf/nan) at the bit level
        unsigned bits = __float_as_uint(r);
        if ((bits & 0x7f800000u) == 0x7f800000u) r = 3.0e38f;
        out[i] = r;
    }
}

extern "C" void kernel_launch(void* const* d_in, const int* in_sizes, int n_in,
                              void* d_out, int out_size, void* d_ws, size_t ws_size,
                              hipStream_t stream) {
    const float* E     = (const float*)d_in[0];
    const float* susc  = (const float*)d_in[1];
    const float* infc  = (const float*)d_in[2];
    const float* incub = (const float*)d_in[3];
    const float* rnd   = (const float*)d_in[4];
    const int*   src   = (const int*)d_in[5];
    const int*   dst   = (const int*)d_in[6];
    int n       = in_sizes[0];
    int n_edges = in_sizes[5];

    float* acc = (float*)d_out;  // acc lives in the output buffer

    const int B = 256;
    int nb_nodes = (n + B - 1) / B;

    int nwords64 = (n + 63) / 64;               // ull words of bitmask
    int nwords32 = (n + 31) / 32;               // u32 words of bitmask
    size_t tables_bytes = (size_t)4 * n;        // sus + infv fp16
    size_t bits_off     = (tables_bytes + 7) & ~(size_t)7;
    size_t ctr_off      = bits_off + (size_t)nwords64 * 8;
    size_t pairs_off    = (ctr_off + 8 + 15) & ~(size_t)15;
    size_t need_lds     = ctr_off;              // tables + bits (R6 path)

    // capacity for compacted pairs
    size_t cap_avail = (ws_size > pairs_off) ? (ws_size - pairs_off) / 8 : 0;
    size_t cap_need  = (size_t)n_edges / 3 + 65536;   // survivors ~30%, huge margin
    if (cap_avail > (size_t)n_edges) cap_avail = (size_t)n_edges;

    if (nwords32 <= MAX_BIT_WORDS && cap_avail >= cap_need) {
        // R8 path: filter/compact + dense process
        __half* sus  = (__half*)d_ws;
        __half* infv = sus + n;
        unsigned long long* gbits = (unsigned long long*)((char*)d_ws + bits_off);
        unsigned int* gctr = (unsigned int*)((char*)d_ws + ctr_off);
        unsigned long long* pairs = (unsigned long long*)((char*)d_ws + pairs_off);
        unsigned int capacity = (unsigned int)cap_avail;

        prep_full<<<nb_nodes, B, 0, stream>>>(E, susc, infc, sus, infv, gbits, gctr, acc, n);
        edge_filter<<<256, 1024, 0, stream>>>(src, dst, (const unsigned int*)gbits,
                                              (const unsigned short*)sus,
                                              (const unsigned short*)infv,
                                              acc, pairs, gctr, capacity,
                                              n_edges, nwords32);
        edge_process<<<2048, 256, 0, stream>>>(pairs, gctr,
                                               (const unsigned short*)sus,
                                               (const unsigned short*)infv,
                                               acc, capacity);
    } else if (ws_size >= need_lds && nwords32 <= MAX_BIT_WORDS) {
        // R6 path: fp16 tables + bitmask, LDS-filtered divergent edges
        __half* sus  = (__half*)d_ws;
        __half* infv = sus + n;
        unsigned long long* gbits = (unsigned long long*)((char*)d_ws + bits_off);
        prep_full<<<nb_nodes, B, 0, stream>>>(E, susc, infc, sus, infv, gbits, nullptr, acc, n);
        edge_lds<<<256, 1024, 0, stream>>>(src, dst, sus, infv,
                                           (const unsigned int*)gbits, acc,
                                           n_edges, nwords32);
    } else if (ws_size >= tables_bytes) {
        // Fallback A: fp16 tables, no bitmask
        __half* sus  = (__half*)d_ws;
        __half* infv = sus + n;
        prep_full<<<nb_nodes, B, 0, stream>>>(E, susc, infc, sus, infv, nullptr, nullptr, acc, n);
        int n_vec = (n_edges + 3) / 4;
        edge_fast<<<(n_vec + B - 1) / B, B, 0, stream>>>(src, dst, sus, infv, acc, n_edges);
    } else {
        // Fallback B: tiny ws
        prep_acc_only<<<nb_nodes, B, 0, stream>>>(acc, n);
        long long nb_e = ((long long)n_edges + B - 1) / B;
        edge_inline<<<(unsigned)nb_e, B, 0, stream>>>(src, dst, E, susc, infc, acc, n_edges);
    }

    final_kernel<<<nb_nodes, B, 0, stream>>>(E, rnd, incub, acc, n);
}